// Round 10
// baseline (158.576 us; speedup 1.0000x reference)
//
#include <hip/hip_runtime.h>

typedef __attribute__((ext_vector_type(8))) short bf16x8;
typedef __attribute__((ext_vector_type(4))) float f32x4;
typedef __attribute__((ext_vector_type(16))) float f32x16;

__device__ __forceinline__ unsigned short f2bf(float f) {
  union { float f; unsigned u; } a; a.f = f;
  unsigned u = a.u;
  u += 0x7fffu + ((u >> 16) & 1u);   // round-to-nearest-even
  return (unsigned short)(u >> 16);
}
__device__ __forceinline__ unsigned pk(float a, float b) {
  return (unsigned)f2bf(a) | ((unsigned)f2bf(b) << 16);
}

// ---------------------------------------------------------------------------
// Prep: build Bt[tap][n][k] bf16 in workspace.
//   n = opc*4 + q_out  (q minor -> acc regs = quaternion comps)
//   k = c*4   + q_in   (q minor -> one float4 pixel-channel = 8B of k)
// ---------------------------------------------------------------------------
__global__ void prep_bt(const float* __restrict__ wr, const float* __restrict__ wi,
                        const float* __restrict__ wj, const float* __restrict__ wk,
                        unsigned short* __restrict__ btg) {
  int idx = blockIdx.x * 256 + threadIdx.x;          // 9*256*256 = 589824
  if (idx >= 9 * 256 * 256) return;
  int tap = idx >> 16;
  int rem = idx & 65535;
  int n = rem >> 8, k = rem & 255;
  int opc = n >> 2, qo = n & 3, c = k >> 2, qi = k & 3;
  const int   comp[4][4] = {{0,1,2,3},{1,0,3,2},{2,3,0,1},{3,2,1,0}};
  const float sgn [4][4] = {{1.f,-1.f,-1.f,-1.f},{1.f,1.f,-1.f,1.f},
                            {1.f,1.f,1.f,-1.f},{1.f,-1.f,1.f,1.f}};
  int ci = comp[qo][qi];
  const float* wp = (ci == 0) ? wr : (ci == 1) ? wi : (ci == 2) ? wj : wk;
  float v = sgn[qo][qi] * wp[(opc * 64 + c) * 9 + tap];
  btg[idx] = f2bf(v);
}

// ---------------------------------------------------------------------------
// Main: implicit-GEMM quaternion conv, 32x32x16 MFMA, FAT-WAVE structure.
// Block 256 thr = 4 waves, ONE WAVE PER SIMD (1 wave/SIMD, ~460 unified regs).
// Block tile 256 px (4 image rows) x 256 N; wave (wm,wn) = 128px x 128N,
// acc[4][4] f32x16 = 256 AGPR. 32 MFMAs (~1033 cyc) per tap per wave ->
// in-wave ILP hides all load latency; only 9 barriers total (1/chunk).
// K: 8 chunks of k=32 (8 channels). X in LDS dbuf (k-slot-major, conflict-
// free); W from L2-resident btg direct to regs, tap-ahead double-buffered;
// pf 1-tap-ahead double-buffered; X staged via 2 register halves issued at
// taps 1/4 (>=2-tap age before any implicit vmcnt drain > HBM latency).
// ---------------------------------------------------------------------------
__launch_bounds__(256, 1)
__global__ void qconv_main(const float* __restrict__ x,
                           const unsigned short* __restrict__ btg,
                           const float* __restrict__ bias,
                           float* __restrict__ out) {
#define XBUF 25344   // [6 rows][4 ks][66 cols] * 16B
  __shared__ char lds[2 * XBUF];   // 50688 B

  const int tid = threadIdx.x;
  // XCD-aware swizzle: 256 blocks, 8 XCDs -> 32 consecutive per XCD
  const int nb  = (blockIdx.x & 7) * 32 + (blockIdx.x >> 3);
  const int b   = nb >> 4;              // image
  const int h0  = (nb & 15) * 4;        // first of 4 image rows

  const int lane = tid & 63;
  const int wid  = tid >> 6;            // 0..3 (one wave per SIMD)
  const int wm   = wid & 1;             // pixel half: image rows 2wm,2wm+1
  const int wn   = wid >> 1;            // N half: n in [wn*128, wn*128+128)
  const int l31  = lane & 31;
  const int l32  = lane >> 5;

  // zero-fill pad cols 0/65 in both buffers: 2 x 6 x 4 x 2 = 96 cells
  if (tid < 96) {
    int par = tid / 48, r = tid % 48;
    int row = r >> 3, ks = (r >> 1) & 3, side = r & 1;
    *reinterpret_cast<f32x4*>(
        lds + par * XBUF + ((row * 4 + ks) * 66 + (side ? 65 : 0)) * 16) =
        (f32x4){0.f, 0.f, 0.f, 0.f};
  }

  f32x16 acc[4][4];
#pragma unroll
  for (int i = 0; i < 4; ++i)
#pragma unroll
    for (int j = 0; j < 4; ++j)
      acc[i][j] = (f32x16)(0.f);

  float4 xrA[6], xrB[6];

  // issue 3 cells (2 float4 each) of half HALF for chunk CH into XR
#define XISSUE(XR, HALF, CH)                                                   \
  do {                                                                         \
    _Pragma("unroll") for (int j = 0; j < 3; ++j) {                            \
      int ci_  = (HALF) * 768 + j * 256 + tid;                                 \
      int row_ = ci_ >> 8, ks_ = (ci_ >> 6) & 3, c64_ = ci_ & 63;              \
      int hp_  = h0 + row_ - 1;                                                \
      int c_   = (CH) * 8 + ks_ * 2;                                           \
      float4 a_ = make_float4(0.f, 0.f, 0.f, 0.f), b_ = a_;                    \
      if (hp_ >= 0 && hp_ < 64) {                                              \
        const float* p_ =                                                      \
            x + (size_t)((((b * 64 + c_) * 64 + hp_) * 64 + c64_) * 4);        \
        a_ = *reinterpret_cast<const float4*>(p_);                             \
        b_ = *reinterpret_cast<const float4*>(p_ + 16384);                     \
      }                                                                        \
      XR[2 * j] = a_; XR[2 * j + 1] = b_;                                      \
    }                                                                          \
  } while (0)

#define XWRITE(XR, HALF, PAR)                                                  \
  do {                                                                         \
    char* xd_ = lds + (PAR) * XBUF;                                            \
    _Pragma("unroll") for (int j = 0; j < 3; ++j) {                            \
      int ci_  = (HALF) * 768 + j * 256 + tid;                                 \
      int row_ = ci_ >> 8, ks_ = (ci_ >> 6) & 3, c64_ = ci_ & 63;              \
      uint4 u_ = make_uint4(pk(XR[2 * j].x, XR[2 * j].y),                      \
                            pk(XR[2 * j].z, XR[2 * j].w),                      \
                            pk(XR[2 * j + 1].x, XR[2 * j + 1].y),              \
                            pk(XR[2 * j + 1].z, XR[2 * j + 1].w));             \
      *reinterpret_cast<uint4*>(                                               \
          xd_ + ((row_ * 4 + ks_) * 66 + c64_ + 1) * 16) = u_;                 \
    }                                                                          \
  } while (0)

  // pf frags for tap T: 8 ds_read_b128 (static imm offsets from vbase)
#define LOADPF(PF, T)                                                          \
  do {                                                                         \
    const int dh_ = (T) / 3 - 1, dw_ = (T) % 3 - 1;                            \
    _Pragma("unroll") for (int kst = 0; kst < 2; ++kst)                        \
      _Pragma("unroll") for (int fm = 0; fm < 4; ++fm) {                       \
        int row6 = 2 * wm + (fm >> 1) + dh_ + 1;                               \
        int col  = (fm & 1) * 32 + l31 + dw_ + 1;                              \
        PF[kst][fm] = *reinterpret_cast<const bf16x8*>(                        \
            buf + ((row6 * 4 + kst * 2 + l32) * 66 + col) * 16);               \
      }                                                                        \
  } while (0)

  // wf frags for tap T: 8 global b128 loads from L2-resident btg
#define LOADWF(WF, T)                                                          \
  do {                                                                         \
    _Pragma("unroll") for (int kst = 0; kst < 2; ++kst)                        \
      _Pragma("unroll") for (int fn = 0; fn < 4; ++fn)                         \
        WF[kst][fn] = *reinterpret_cast<const bf16x8*>(                        \
            wb + (size_t)(T) * 65536 + fn * 8192 + kst * 16);                  \
  } while (0)

#define MFMAS(WF, PF)                                                          \
  do {                                                                         \
    _Pragma("unroll") for (int kst = 0; kst < 2; ++kst)                        \
      _Pragma("unroll") for (int fn = 0; fn < 4; ++fn)                         \
        _Pragma("unroll") for (int fm = 0; fm < 4; ++fm)                       \
          acc[fn][fm] = __builtin_amdgcn_mfma_f32_32x32x16_bf16(               \
              WF[kst][fn], PF[kst][fm], acc[fn][fm], 0, 0, 0);                 \
  } while (0)

  // ---- prologue: stage chunk 0 into buf0 ----
  XISSUE(xrA, 0, 0);
  XISSUE(xrB, 1, 0);
  XWRITE(xrA, 0, 0);
  XWRITE(xrB, 1, 0);
  __syncthreads();

#pragma unroll 1
  for (int h = 0; h < 8; ++h) {
    const char* buf = lds + (h & 1) * XBUF;
    const unsigned short* wb =
        btg + (size_t)(wn * 128 + l31) * 256 + h * 32 + l32 * 8;
    const int hn = (h < 7) ? h + 1 : 7;   // clamp: keeps ISSUE unconditional

    bf16x8 pf0[2][4], pf1[2][4], wf0[2][4], wf1[2][4];
    LOADPF(pf0, 0);
    LOADWF(wf0, 0);

#pragma unroll
    for (int t = 0; t < 9; ++t) {
      if (t < 8) {
        if (t & 1) { LOADPF(pf0, t + 1); LOADWF(wf0, t + 1); }
        else       { LOADPF(pf1, t + 1); LOADWF(wf1, t + 1); }
      }
      if (t == 1) XISSUE(xrA, 0, hn);
      if (t == 4) XISSUE(xrB, 1, hn);
      if (t & 1) MFMAS(wf1, pf1);
      else       MFMAS(wf0, pf0);
    }

    if (h < 7) {
      XWRITE(xrA, 0, (h + 1) & 1);
      XWRITE(xrB, 1, (h + 1) & 1);
    }
    __syncthreads();
  }

  // ---- epilogue: D row=(reg&3)+8*(reg>>2)+4*l32 -> reg&3 == q component ----
#pragma unroll
  for (int fn = 0; fn < 4; ++fn) {
#pragma unroll
    for (int fm = 0; fm < 4; ++fm) {
      int w  = (fm & 1) * 32 + l31;
      int hh = h0 + 2 * wm + (fm >> 1);
#pragma unroll
      for (int g = 0; g < 4; ++g) {
        int opc = wn * 32 + fn * 8 + g * 2 + l32;
        f32x4 v = {acc[fn][fm][4 * g + 0], acc[fn][fm][4 * g + 1],
                   acc[fn][fm][4 * g + 2], acc[fn][fm][4 * g + 3]};
        v.x += bias[opc];   // bias only on real component
        *reinterpret_cast<f32x4*>(
            out + (size_t)((((b * 64 + opc) * 64 + hh) * 64 + w) * 4)) = v;
      }
    }
  }
#undef XISSUE
#undef XWRITE
#undef LOADPF
#undef LOADWF
#undef MFMAS
#undef XBUF
}

extern "C" void kernel_launch(void* const* d_in, const int* in_sizes, int n_in,
                              void* d_out, int out_size, void* d_ws, size_t ws_size,
                              hipStream_t stream) {
  const float* x    = (const float*)d_in[0];
  const float* wr   = (const float*)d_in[1];
  const float* wi   = (const float*)d_in[2];
  const float* wj   = (const float*)d_in[3];
  const float* wk   = (const float*)d_in[4];
  const float* bias = (const float*)d_in[5];
  unsigned short* btg = (unsigned short*)d_ws;   // 9*256*256*2 = 1.18 MB

  prep_bt<<<2304, 256, 0, stream>>>(wr, wi, wj, wk, btg);
  qconv_main<<<256, 256, 0, stream>>>(x, btg, bias, (float*)d_out);
}

// Round 11
// 131.582 us; speedup vs baseline: 1.2052x; 1.2052x over previous
//
#include <hip/hip_runtime.h>

typedef __attribute__((ext_vector_type(8))) short bf16x8;
typedef __attribute__((ext_vector_type(4))) float f32x4;
typedef __attribute__((ext_vector_type(16))) float f32x16;

__device__ __forceinline__ unsigned short f2bf(float f) {
  union { float f; unsigned u; } a; a.f = f;
  unsigned u = a.u;
  u += 0x7fffu + ((u >> 16) & 1u);   // round-to-nearest-even
  return (unsigned short)(u >> 16);
}
__device__ __forceinline__ unsigned pk(float a, float b) {
  return (unsigned)f2bf(a) | ((unsigned)f2bf(b) << 16);
}

// ---------------------------------------------------------------------------
// Prep: build Bt[tap][n][k] bf16 in workspace.
//   n = opc*4 + q_out  (q minor -> acc regs = quaternion comps)
//   k = c*4   + q_in   (q minor -> one float4 pixel-channel = 8B of k)
// ---------------------------------------------------------------------------
__global__ void prep_bt(const float* __restrict__ wr, const float* __restrict__ wi,
                        const float* __restrict__ wj, const float* __restrict__ wk,
                        unsigned short* __restrict__ btg) {
  int idx = blockIdx.x * 256 + threadIdx.x;          // 9*256*256 = 589824
  if (idx >= 9 * 256 * 256) return;
  int tap = idx >> 16;
  int rem = idx & 65535;
  int n = rem >> 8, k = rem & 255;
  int opc = n >> 2, qo = n & 3, c = k >> 2, qi = k & 3;
  const int   comp[4][4] = {{0,1,2,3},{1,0,3,2},{2,3,0,1},{3,2,1,0}};
  const float sgn [4][4] = {{1.f,-1.f,-1.f,-1.f},{1.f,1.f,-1.f,1.f},
                            {1.f,1.f,1.f,-1.f},{1.f,-1.f,1.f,1.f}};
  int ci = comp[qo][qi];
  const float* wp = (ci == 0) ? wr : (ci == 1) ? wi : (ci == 2) ? wj : wk;
  float v = sgn[qo][qi] * wp[(opc * 64 + c) * 9 + tap];
  btg[idx] = f2bf(v);
}

// ---------------------------------------------------------------------------
// Main: implicit-GEMM quaternion conv, 32x32x16 MFMA, fat-wave (no-spill).
// Block 256 thr = 4 waves, 1 wave/SIMD; grid 256 = 1 block/CU.
// Block tile 256 px (4 rows) x 256 N; wave (wm,wn) = 128 px x 128 N.
// acc[4][4] f32x16 = 256 AGPR; VGPR side kept ~180: pf/wf dbuf (manually
// peeled taps, static names), X staged in 3 sequential 16-reg slices.
// Pipe budget per tap per CU: MFMA 1030 cyc/SIMD | LDS pf 384 cyc (37%) |
// wf from L2 546 cyc (53%) -> matrix pipe is the dominant consumer.
// LDS: X dbuf [6 rows][4 ks][66 col]x16B (k-slot-major, conflict-free).
// ---------------------------------------------------------------------------
__launch_bounds__(256, 1)
__global__ void qconv_main(const float* __restrict__ x,
                           const unsigned short* __restrict__ btg,
                           const float* __restrict__ bias,
                           float* __restrict__ out) {
#define XBUF 25344   // [6][4][66] * 16B
  __shared__ char lds[2 * XBUF];   // 50688 B

  const int tid = threadIdx.x;
  // XCD-aware swizzle: 256 blocks, 8 XCDs -> 32 consecutive per XCD
  const int nb  = (blockIdx.x & 7) * 32 + (blockIdx.x >> 3);
  const int b   = nb >> 4;              // image
  const int h0  = (nb & 15) * 4;        // first of 4 image rows

  const int lane = tid & 63;
  const int wid  = tid >> 6;            // 0..3, one wave per SIMD
  const int wm   = wid & 1;             // pixel half: image rows 2wm, 2wm+1
  const int wn   = wid >> 1;            // N half: n in [wn*128, wn*128+128)
  const int l31  = lane & 31;
  const int l32  = lane >> 5;

  // zero pad cols 0/65: 24 cells x 2 sides x 2 buffers = 96 x 16B
  if (tid < 96) {
    int par = tid / 48, r = tid % 48;
    int ci = r >> 1, col = (r & 1) ? 65 : 0;
    *reinterpret_cast<f32x4*>(lds + par * XBUF + (ci * 66 + col) * 16) =
        (f32x4){0.f, 0.f, 0.f, 0.f};
  }

  f32x16 acc[4][4];
#pragma unroll
  for (int i = 0; i < 4; ++i)
#pragma unroll
    for (int j = 0; j < 4; ++j)
      acc[i][j] = (f32x16)(0.f);

  float4 xr[4];   // one slice in flight: 2 cells x 2 channels

  // slice S (0..2) of chunk CH: this wave's 2 cells, col = lane
#define SLICE_ISSUE(S, CH)                                                     \
  do {                                                                         \
    _Pragma("unroll") for (int cc = 0; cc < 2; ++cc) {                         \
      int ci_  = 8 * (S) + 2 * wid + cc;                                       \
      int row_ = ci_ >> 2, ks_ = ci_ & 3;                                      \
      int hp_  = h0 + row_ - 1;                                                \
      int c0_  = (CH) * 8 + ks_ * 2;                                           \
      float4 a_ = make_float4(0.f, 0.f, 0.f, 0.f), b2_ = a_;                   \
      if (hp_ >= 0 && hp_ < 64) {                                              \
        const float* p_ =                                                      \
            x + (size_t)((((b * 64 + c0_) * 64 + hp_) * 64 + lane) * 4);       \
        a_  = *reinterpret_cast<const float4*>(p_);                            \
        b2_ = *reinterpret_cast<const float4*>(p_ + 16384);                    \
      }                                                                        \
      xr[2 * cc] = a_; xr[2 * cc + 1] = b2_;                                   \
    }                                                                          \
  } while (0)

#define SLICE_WRITE(S, XD)                                                     \
  do {                                                                         \
    _Pragma("unroll") for (int cc = 0; cc < 2; ++cc) {                         \
      int ci_ = 8 * (S) + 2 * wid + cc;                                        \
      uint4 u_ = make_uint4(pk(xr[2 * cc].x, xr[2 * cc].y),                    \
                            pk(xr[2 * cc].z, xr[2 * cc].w),                    \
                            pk(xr[2 * cc + 1].x, xr[2 * cc + 1].y),            \
                            pk(xr[2 * cc + 1].z, xr[2 * cc + 1].w));           \
      *reinterpret_cast<uint4*>((XD) + (ci_ * 66 + lane + 1) * 16) = u_;       \
    }                                                                          \
  } while (0)

#define LOADPF(PF, T)                                                          \
  do {                                                                         \
    const int dh_ = (T) / 3 - 1, dw_ = (T) % 3 - 1;                            \
    _Pragma("unroll") for (int kst = 0; kst < 2; ++kst)                        \
      _Pragma("unroll") for (int fm = 0; fm < 4; ++fm) {                       \
        int row6 = 2 * wm + (fm >> 1) + dh_ + 1;                               \
        int col  = (fm & 1) * 32 + l31 + dw_ + 1;                              \
        PF[kst][fm] = *reinterpret_cast<const bf16x8*>(                        \
            buf + ((row6 * 4 + kst * 2 + l32) * 66 + col) * 16);               \
      }                                                                        \
  } while (0)

#define LOADWF(WF, T)                                                          \
  do {                                                                         \
    _Pragma("unroll") for (int kst = 0; kst < 2; ++kst)                        \
      _Pragma("unroll") for (int fn = 0; fn < 4; ++fn)                         \
        WF[kst][fn] = *reinterpret_cast<const bf16x8*>(                        \
            wb + (size_t)(T) * 65536 + fn * 8192 + kst * 16);                  \
  } while (0)

#define MFMAS(WF, PF)                                                          \
  do {                                                                         \
    _Pragma("unroll") for (int kst = 0; kst < 2; ++kst)                        \
      _Pragma("unroll") for (int fn = 0; fn < 4; ++fn)                         \
        _Pragma("unroll") for (int fm = 0; fm < 4; ++fm)                       \
          acc[fn][fm] = __builtin_amdgcn_mfma_f32_32x32x16_bf16(               \
              WF[kst][fn], PF[kst][fm], acc[fn][fm], 0, 0, 0);                 \
  } while (0)

  // ---- prologue: stage chunk 0 into buf0 ----
  {
    char* xd = lds;
    SLICE_ISSUE(0, 0); SLICE_WRITE(0, xd);
    SLICE_ISSUE(1, 0); SLICE_WRITE(1, xd);
    SLICE_ISSUE(2, 0); SLICE_WRITE(2, xd);
  }
  __syncthreads();

#pragma unroll 1
  for (int h = 0; h < 8; ++h) {
    const char* buf = lds + (h & 1) * XBUF;
    char* xd = lds + ((h + 1) & 1) * XBUF;
    const unsigned short* wb =
        btg + (size_t)(wn * 128 + l31) * 256 + h * 32 + l32 * 8;
    const bool stage = (h < 7);

    bf16x8 pf0[2][4], pf1[2][4], wf0[2][4], wf1[2][4];
    LOADPF(pf0, 0); LOADWF(wf0, 0);

    // t = 0
    LOADPF(pf1, 1); LOADWF(wf1, 1);
    MFMAS(wf0, pf0);
    // t = 1
    LOADPF(pf0, 2); LOADWF(wf0, 2);
    if (stage) SLICE_ISSUE(0, h + 1);
    MFMAS(wf1, pf1);
    // t = 2
    LOADPF(pf1, 3); LOADWF(wf1, 3);
    MFMAS(wf0, pf0);
    // t = 3
    LOADPF(pf0, 4); LOADWF(wf0, 4);
    MFMAS(wf1, pf1);
    // t = 4
    LOADPF(pf1, 5); LOADWF(wf1, 5);
    if (stage) { SLICE_WRITE(0, xd); SLICE_ISSUE(1, h + 1); }
    MFMAS(wf0, pf0);
    // t = 5
    LOADPF(pf0, 6); LOADWF(wf0, 6);
    MFMAS(wf1, pf1);
    // t = 6
    LOADPF(pf1, 7); LOADWF(wf1, 7);
    if (stage) { SLICE_WRITE(1, xd); SLICE_ISSUE(2, h + 1); }
    MFMAS(wf0, pf0);
    // t = 7
    LOADPF(pf0, 8); LOADWF(wf0, 8);
    MFMAS(wf1, pf1);
    // t = 8
    if (stage) SLICE_WRITE(2, xd);
    MFMAS(wf0, pf0);

    __syncthreads();
  }

  // ---- epilogue: D row=(reg&3)+8*(reg>>2)+4*l32 -> reg&3 == q component ----
#pragma unroll
  for (int fn = 0; fn < 4; ++fn) {
#pragma unroll
    for (int fm = 0; fm < 4; ++fm) {
      int w  = (fm & 1) * 32 + l31;
      int hh = h0 + 2 * wm + (fm >> 1);
#pragma unroll
      for (int g = 0; g < 4; ++g) {
        int opc = wn * 32 + fn * 8 + g * 2 + l32;
        f32x4 v = {acc[fn][fm][4 * g + 0], acc[fn][fm][4 * g + 1],
                   acc[fn][fm][4 * g + 2], acc[fn][fm][4 * g + 3]};
        v.x += bias[opc];   // bias only on real component
        *reinterpret_cast<f32x4*>(
            out + (size_t)((((b * 64 + opc) * 64 + hh) * 64 + w) * 4)) = v;
      }
    }
  }
#undef SLICE_ISSUE
#undef SLICE_WRITE
#undef LOADPF
#undef LOADWF
#undef MFMAS
#undef XBUF
}

extern "C" void kernel_launch(void* const* d_in, const int* in_sizes, int n_in,
                              void* d_out, int out_size, void* d_ws, size_t ws_size,
                              hipStream_t stream) {
  const float* x    = (const float*)d_in[0];
  const float* wr   = (const float*)d_in[1];
  const float* wi   = (const float*)d_in[2];
  const float* wj   = (const float*)d_in[3];
  const float* wk   = (const float*)d_in[4];
  const float* bias = (const float*)d_in[5];
  unsigned short* btg = (unsigned short*)d_ws;   // 9*256*256*2 = 1.18 MB

  prep_bt<<<2304, 256, 0, stream>>>(wr, wi, wj, wk, btg);
  qconv_main<<<256, 256, 0, stream>>>(x, btg, bias, (float*)d_out);
}